// Round 1
// baseline (47.604 us; speedup 1.0000x reference)
//
#include <hip/hip_runtime.h>

#define STEP 100
#define NGUESS 256
#define CPG 20   // chunks per rank-block

__device__ __constant__ int SBOXD[256] = {
  99, 124, 119, 123, 242, 107, 111, 197, 48, 1, 103, 43, 254, 215, 171, 118,
  202, 130, 201, 125, 250, 89, 71, 240, 173, 212, 162, 175, 156, 164, 114, 192,
  183, 253, 147, 38, 54, 63, 247, 204, 52, 165, 229, 241, 113, 216, 49, 21,
  4, 199, 35, 195, 24, 150, 5, 154, 7, 18, 128, 226, 235, 39, 178, 117,
  9, 131, 44, 26, 27, 110, 90, 160, 82, 59, 214, 179, 41, 227, 47, 132,
  83, 209, 0, 237, 32, 252, 177, 91, 106, 203, 190, 57, 74, 76, 88, 207,
  208, 239, 170, 251, 67, 77, 51, 133, 69, 249, 2, 127, 80, 60, 159, 168,
  81, 163, 64, 143, 146, 157, 56, 245, 188, 182, 218, 33, 16, 255, 243, 210,
  205, 12, 19, 236, 95, 151, 68, 23, 196, 167, 126, 61, 100, 93, 25, 115,
  96, 129, 79, 220, 34, 42, 144, 136, 70, 238, 184, 20, 222, 94, 11, 219,
  224, 50, 58, 10, 73, 6, 36, 92, 194, 211, 172, 98, 145, 149, 228, 121,
  231, 200, 55, 109, 141, 213, 78, 169, 108, 86, 244, 234, 101, 122, 174, 8,
  186, 120, 37, 46, 28, 166, 180, 198, 232, 221, 116, 31, 75, 189, 139, 138,
  112, 62, 181, 102, 72, 3, 246, 14, 97, 53, 87, 185, 134, 193, 29, 158,
  225, 248, 152, 17, 105, 217, 142, 148, 155, 30, 135, 233, 206, 85, 40, 223,
  140, 161, 137, 13, 191, 230, 66, 104, 65, 153, 45, 15, 176, 84, 187, 22
};

// K1: one block per chunk (100 rows x 256 cols). Stage 4 rows at a time into
// LDS (coalesced float4, log applied on the way in), then each thread g
// accumulates its guess column via the sbox permutation gather from LDS.
__global__ __launch_bounds__(256) void k_chunksums(const float* __restrict__ pred,
                                                   const int* __restrict__ meta,
                                                   float* __restrict__ cs) {
  __shared__ float lrow[4][256];
  __shared__ int sboxs[256];
  const int g = threadIdx.x;
  const int chunk = blockIdx.x;
  const long base = (long)chunk * STEP;
  sboxs[g] = SBOXD[g];
  const int rr = g >> 6;          // which of the 4 staged rows this thread loads
  const int c4 = (g & 63) << 2;   // column (float4 granularity)
  float acc = 0.f;
  for (int r0 = 0; r0 < STEP; r0 += 4) {
    const float4 v = *reinterpret_cast<const float4*>(pred + (base + r0 + rr) * NGUESS + c4);
    float l0 = (v.x != 0.f) ? logf(v.x) : 0.f;
    float l1 = (v.y != 0.f) ? logf(v.y) : 0.f;
    float l2 = (v.z != 0.f) ? logf(v.z) : 0.f;
    float l3 = (v.w != 0.f) ? logf(v.w) : 0.f;
    __syncthreads();   // previous iteration's readers done (also covers sboxs)
    lrow[rr][c4 + 0] = l0;
    lrow[rr][c4 + 1] = l1;
    lrow[rr][c4 + 2] = l2;
    lrow[rr][c4 + 3] = l3;
    __syncthreads();
#pragma unroll
    for (int k = 0; k < 4; ++k) {
      const int m = meta[base + r0 + k];   // wave-uniform
      acc += lrow[k][sboxs[m ^ g]];
    }
  }
  cs[chunk * NGUESS + g] = acc;
}

// K2a: per-group (20-chunk) sums in double, for fast prefix derivation.
__global__ __launch_bounds__(256) void k_groupsum(const float* __restrict__ cs,
                                                  double* __restrict__ gsum) {
  const int b = blockIdx.x, g = threadIdx.x;
  double s = 0.0;
#pragma unroll
  for (int c = 0; c < CPG; ++c) s += (double)cs[(b * CPG + c) * NGUESS + g];
  gsum[b * NGUESS + g] = s;
}

// K2c: each block handles 20 chunks; derives its cumsum prefix from group
// sums, then per chunk computes rank = #(score > key_score) via ballot.
__global__ __launch_bounds__(256) void k_ranks(const float* __restrict__ cs,
                                               const double* __restrict__ gsum,
                                               const int* __restrict__ ckp,
                                               int* __restrict__ outRanks,
                                               int* __restrict__ outX) {
  const int b = blockIdx.x, g = threadIdx.x;
  const int ck = *ckp;
  double acc = 0.0;
  for (int bb = 0; bb < b; ++bb) acc += gsum[bb * NGUESS + g];
  __shared__ double keysh;
  __shared__ int cnt;
  for (int c = 0; c < CPG; ++c) {
    const int chunk = b * CPG + c;
    acc += (double)cs[chunk * NGUESS + g];
    if (g == ck) keysh = acc;
    if (g == 0) cnt = 0;
    __syncthreads();
    const int p = (acc > keysh) ? 1 : 0;
    const unsigned long long m = __ballot(p);
    if ((g & 63) == 0) atomicAdd(&cnt, (int)__popcll(m));
    __syncthreads();
    if (g == 0) outRanks[chunk] = cnt;
  }
  if (g < CPG) {
    const int chunk = b * CPG + g;
    outX[chunk] = (chunk + 1) * STEP;
  }
}

extern "C" void kernel_launch(void* const* d_in, const int* in_sizes, int n_in,
                              void* d_out, int out_size, void* d_ws, size_t ws_size,
                              hipStream_t stream) {
  const float* pred = (const float*)d_in[0];
  const int* meta   = (const int*)d_in[1];
  // d_in[2] = guess_range (256), d_in[3] = correct_key (34), d_in[4] = step (100)
  const int* ckp    = (const int*)d_in[3];

  const int N = in_sizes[1];          // 100000
  const int num_chunks = N / STEP;    // 1000
  const int ngroups = num_chunks / CPG; // 50

  float*  cs   = (float*)d_ws;                                    // [1000][256] f32
  double* gsum = (double*)((char*)d_ws +
                           (size_t)num_chunks * NGUESS * sizeof(float)); // [50][256] f64

  int* out = (int*)d_out;             // ranks[0..nc), x_rank[nc..2nc)

  k_chunksums<<<num_chunks, 256, 0, stream>>>(pred, meta, cs);
  k_groupsum <<<ngroups,   256, 0, stream>>>(cs, gsum);
  k_ranks    <<<ngroups,   256, 0, stream>>>(cs, gsum, ckp, out, out + num_chunks);
}